// Round 5
// baseline (311.120 us; speedup 1.0000x reference)
//
#include <hip/hip_runtime.h>
#include <stdint.h>
#include <math.h>

// Binary bottleneck: sign-threshold trick collapses conv1/conv2 + BN + PReLU
// into integer popcount + per-channel threshold. Only conv3 output needs floats.
// R5: BISECT arm 2 — k1/k2 vectorized (4 px/thread, float4/uint4);
// k3 byte-identical to passing R1 scalar version (the k3-float4 variant is
// the proven failure across R2/R3/R4).

#define EPS 1e-5f
constexpr int B = 8, C = 128, Ci = 32, H = 128, W = 256;
constexpr int HW = H * W;      // 32768 = 2^15
constexpr int HW4 = HW / 4;    // 8192  = 2^13
constexpr int P  = B * HW;     // 262144 pixels total

// ws layout (uint32 units):
// [0,128)    w1p | [128,416) w2p | [416,544) w3p
// [544,576)  T1  | [576,608) T2  | [608,736) inv3 | [736,864) c3
// [1024, 1024+P) s1 | [1024+P, 1024+2P) s2
constexpr int WS_S1 = 1024;
constexpr int WS_S2 = 1024 + P;

__global__ __launch_bounds__(256) void prep_kernel(
    const float* __restrict__ w1,
    const float* __restrict__ g1, const float* __restrict__ b1,
    const float* __restrict__ m1, const float* __restrict__ v1,
    const float* __restrict__ w2,
    const float* __restrict__ g2, const float* __restrict__ b2,
    const float* __restrict__ m2, const float* __restrict__ v2,
    const float* __restrict__ w3,
    const float* __restrict__ g3, const float* __restrict__ b3,
    const float* __restrict__ m3, const float* __restrict__ v3,
    uint32_t* __restrict__ ws)
{
    int t = threadIdx.x;
    float* wsf = (float*)ws;

    if (t < 128) {  // w1 pack: ci = t>>2, word = t&3
        int ci = t >> 2, wd = t & 3;
        const float* src = w1 + ci * C + wd * 32;
        uint32_t m = 0;
        #pragma unroll
        for (int j = 0; j < 32; ++j) m |= (src[j] > 0.f ? 1u : 0u) << j;
        ws[t] = m;
    }
    for (int idx = t; idx < 288; idx += 256) {  // w2 pack: ci = idx/9, tap = idx%9
        int ci = idx / 9, tap = idx % 9;
        uint32_t m = 0;
        for (int cj = 0; cj < 32; ++cj)
            m |= (w2[(ci * Ci + cj) * 9 + tap] > 0.f ? 1u : 0u) << cj;
        ws[128 + idx] = m;
    }
    if (t < 128) {  // w3 pack
        const float* src = w3 + t * Ci;
        uint32_t m = 0;
        #pragma unroll
        for (int j = 0; j < 32; ++j) m |= (src[j] > 0.f ? 1u : 0u) << j;
        ws[416 + t] = m;
    }
    if (t < 32) {   // thresholds: T = m - b*sqrt(v+EPS)/g  (h<=0 <=> y<=T)
        float inv1 = g1[t] / sqrtf(v1[t] + EPS);
        wsf[544 + t] = m1[t] - b1[t] / inv1;
        float inv2 = g2[t] / sqrtf(v2[t] + EPS);
        wsf[576 + t] = m2[t] - b2[t] / inv2;
    }
    if (t < 128) {  // bn3 constants
        float i3 = g3[t] / sqrtf(v3[t] + EPS);
        wsf[608 + t] = i3;
        wsf[736 + t] = b3[t] - m3[t] * i3;
    }
}

// k1: x -> s1. 4 pixels/thread, float4 loads, 1x1 binconv popcount + threshold.
__global__ __launch_bounds__(256) void k1_kernel(
    const float4* __restrict__ x4, const uint32_t* __restrict__ ws,
    uint4* __restrict__ s1v)
{
    __shared__ uint32_t w1p[128];
    __shared__ float T1[32];
    int t = threadIdx.x;
    if (t < 128) w1p[t] = ws[t];
    if (t < 32)  T1[t] = ((const float*)ws)[544 + t];
    __syncthreads();

    int g  = blockIdx.x * 256 + t;   // strip index, 0..65535
    int b  = g >> 13;                // / HW4
    int r4 = g & (HW4 - 1);
    const float4* xb = x4 + (size_t)b * C * HW4 + r4;

    uint32_t m[4][4];                // [pixel][word]
    #pragma unroll
    for (int wd = 0; wd < 4; ++wd) {
        uint32_t a0 = 0, a1 = 0, a2 = 0, a3 = 0;
        #pragma unroll
        for (int j = 0; j < 32; ++j) {
            float4 v = xb[(size_t)(wd * 32 + j) * HW4];
            a0 |= (v.x > 0.f ? 1u : 0u) << j;
            a1 |= (v.y > 0.f ? 1u : 0u) << j;
            a2 |= (v.z > 0.f ? 1u : 0u) << j;
            a3 |= (v.w > 0.f ? 1u : 0u) << j;
        }
        m[0][wd] = a0; m[1][wd] = a1; m[2][wd] = a2; m[3][wd] = a3;
    }

    uint32_t o[4] = {0, 0, 0, 0};
    #pragma unroll
    for (int ci = 0; ci < 32; ++ci) {
        uint32_t q0 = w1p[ci*4], q1 = w1p[ci*4+1], q2 = w1p[ci*4+2], q3 = w1p[ci*4+3];
        float T = T1[ci];
        #pragma unroll
        for (int k = 0; k < 4; ++k) {
            int neq = __popc(m[k][0]^q0) + __popc(m[k][1]^q1)
                    + __popc(m[k][2]^q2) + __popc(m[k][3]^q3);
            o[k] |= ((float)(128 - 2*neq) > T ? 1u : 0u) << ci;
        }
    }
    s1v[g] = make_uint4(o[0], o[1], o[2], o[3]);
}

// k2: s1 -> s2. 4 pixels/thread. 3x3 binconv, zero-pad taps excluded via masks.
__global__ __launch_bounds__(256) void k2_kernel(
    const uint32_t* __restrict__ s1, const uint32_t* __restrict__ ws,
    uint4* __restrict__ s2v)
{
    __shared__ uint32_t w2p[288];
    __shared__ float T2[32];
    int t = threadIdx.x;
    for (int i = t; i < 288; i += 256) w2p[i] = ws[128 + i];
    if (t < 32) T2[t] = ((const float*)ws)[576 + t];
    __syncthreads();

    int g   = blockIdx.x * 256 + t;
    int p0  = g << 2;
    int b   = p0 >> 15;
    int rem = p0 & (HW - 1);
    int h   = rem >> 8;
    int w   = rem & 255;             // multiple of 4

    bool leftok = (w > 0), rightok = (w < 252);
    uint32_t arr[3][6];              // words at x-positions w-1 .. w+4
    bool rowok[3];
    #pragma unroll
    for (int r = 0; r < 3; ++r) {
        int hh = h + r - 1;
        bool ok = (hh >= 0) && (hh < H);
        rowok[r] = ok;
        int idx = b * HW + hh * W + w;
        uint4 mid = make_uint4(0u, 0u, 0u, 0u);
        if (ok) mid = *(const uint4*)(s1 + idx);
        arr[r][1] = mid.x; arr[r][2] = mid.y; arr[r][3] = mid.z; arr[r][4] = mid.w;
        arr[r][0] = (ok && leftok)  ? s1[idx - 1] : 0u;
        arr[r][5] = (ok && rightok) ? s1[idx + 4] : 0u;
    }
    bool wok[6] = {leftok, true, true, true, true, rightok};

    uint32_t o[4];
    #pragma unroll
    for (int i = 0; i < 4; ++i) {    // pixel in strip; tap dxi uses word i+dxi
        bool tv[9];
        int nv = 0;
        #pragma unroll
        for (int r = 0; r < 3; ++r)
            #pragma unroll
            for (int dxi = 0; dxi < 3; ++dxi) {
                bool v = rowok[r] && wok[i + dxi];
                tv[r*3 + dxi] = v;
                nv += v ? 1 : 0;
            }
        float base2 = (float)(32 * nv);
        uint32_t ob = 0;
        #pragma unroll
        for (int ci = 0; ci < 32; ++ci) {
            int neq = 0;
            #pragma unroll
            for (int r = 0; r < 3; ++r)
                #pragma unroll
                for (int dxi = 0; dxi < 3; ++dxi) {
                    int pc = __popc(arr[r][i + dxi] ^ w2p[ci*9 + r*3 + dxi]);
                    neq += tv[r*3 + dxi] ? pc : 0;
                }
            ob |= ((base2 - (float)(2*neq)) > T2[ci] ? 1u : 0u) << ci;
        }
        o[i] = ob;
    }
    s2v[g] = make_uint4(o[0], o[1], o[2], o[3]);
}

// k3: s2 + x -> out  (1x1 expand popcount, BN3, PReLU, residual, PReLU)
// BYTE-IDENTICAL to passing R1.
__global__ __launch_bounds__(256) void k3_kernel(
    const float* __restrict__ x, const uint32_t* __restrict__ s2,
    const uint32_t* __restrict__ ws,
    const float* __restrict__ a3p, const float* __restrict__ aoutp,
    float* __restrict__ out)
{
    __shared__ uint32_t w3p[128];
    __shared__ float inv3[128], c3[128];
    int t = threadIdx.x;
    if (t < 128) {
        w3p[t]  = ws[416 + t];
        inv3[t] = ((const float*)ws)[608 + t];
        c3[t]   = ((const float*)ws)[736 + t];
    }
    __syncthreads();

    float a3 = a3p[0], aout = aoutp[0];
    int p   = blockIdx.x * 256 + t;
    int b   = p >> 15;
    int rem = p & (HW - 1);
    size_t base = (size_t)b * C * HW + rem;
    uint32_t sw = s2[p];

    #pragma unroll 8
    for (int c = 0; c < C; ++c) {
        int y3 = 32 - 2 * __popc(sw ^ w3p[c]);
        float hv = fmaf((float)y3, inv3[c], c3[c]);
        hv = hv < 0.f ? a3 * hv : hv;
        float o = hv + x[base + (size_t)c * HW];
        o = o < 0.f ? aout * o : o;
        out[base + (size_t)c * HW] = o;
    }
}

extern "C" void kernel_launch(void* const* d_in, const int* in_sizes, int n_in,
                              void* d_out, int out_size, void* d_ws, size_t ws_size,
                              hipStream_t stream)
{
    const float* x  = (const float*)d_in[0];
    const float* w1 = (const float*)d_in[1];
    const float* g1 = (const float*)d_in[2];
    const float* b1 = (const float*)d_in[3];
    const float* m1 = (const float*)d_in[4];
    const float* v1 = (const float*)d_in[5];
    const float* w2 = (const float*)d_in[7];
    const float* g2 = (const float*)d_in[8];
    const float* b2 = (const float*)d_in[9];
    const float* m2 = (const float*)d_in[10];
    const float* v2 = (const float*)d_in[11];
    const float* w3 = (const float*)d_in[13];
    const float* g3 = (const float*)d_in[14];
    const float* b3 = (const float*)d_in[15];
    const float* m3 = (const float*)d_in[16];
    const float* v3 = (const float*)d_in[17];
    const float* a3 = (const float*)d_in[18];
    const float* ao = (const float*)d_in[19];

    uint32_t* ws = (uint32_t*)d_ws;
    uint32_t* s1 = ws + WS_S1;
    uint32_t* s2 = ws + WS_S2;

    hipLaunchKernelGGL(prep_kernel, dim3(1), dim3(256), 0, stream,
                       w1, g1, b1, m1, v1, w2, g2, b2, m2, v2, w3, g3, b3, m3, v3, ws);
    hipLaunchKernelGGL(k1_kernel, dim3(P / 1024), dim3(256), 0, stream,
                       (const float4*)x, ws, (uint4*)s1);
    hipLaunchKernelGGL(k2_kernel, dim3(P / 1024), dim3(256), 0, stream,
                       s1, ws, (uint4*)s2);
    hipLaunchKernelGGL(k3_kernel, dim3(P / 256), dim3(256), 0, stream,
                       x, s2, ws, a3, ao, (float*)d_out);
}